// Round 7
// baseline (175.410 us; speedup 1.0000x reference)
//
#include <hip/hip_runtime.h>
#include <hip/hip_bf16.h>

// HeadLayer: B=8, S=2048, E=1024, H=64.
// Inputs (fp32): x[B,S,E], Wq[E,H], Wk[E,H], Wv[E,H]. Output (fp32): [B,S,H].
// ws (bf16): qb[B,S,H] (pre-scaled 1/32), kb[B,S,H], vtb[B,H,S], Wt[192][1024].

#define BATCH 8
#define SEQ   2048
#define EMB   1024
#define HD    64
#define ROWS  (BATCH*SEQ)      // 16384
#define NTOT  192

typedef __attribute__((ext_vector_type(8))) short short8;   // 8 bf16 (4 VGPR)
typedef __attribute__((ext_vector_type(4))) float floatx4;  // MFMA C/D frag

static __device__ __forceinline__ short f2bf(float f) {
  union { __hip_bfloat16 h; short s; } u;
  u.h = __float2bfloat16(f);
  return u.s;
}

// ---------------- W transpose pre-pass --------------------------------------
__global__ __launch_bounds__(256) void wt_kernel(
    const float* __restrict__ Wq, const float* __restrict__ Wk,
    const float* __restrict__ Wv, short* __restrict__ Wt) {
  const int i = blockIdx.x * 256 + threadIdx.x;   // 0..49151
  const int np = i % NTOT;
  const int c4 = i / NTOT;                        // 0..255
  const float* __restrict__ W = (np < 64) ? Wq : ((np < 128) ? Wk : Wv);
  const int n = np & 63;
  short4 o;
  o.x = f2bf(W[(c4 * 4 + 0) * HD + n]);
  o.y = f2bf(W[(c4 * 4 + 1) * HD + n]);
  o.z = f2bf(W[(c4 * 4 + 2) * HD + n]);
  o.w = f2bf(W[(c4 * 4 + 3) * HD + n]);
  *(short4*)(Wt + (size_t)np * EMB + c4 * 4) = o;
}

// ---------------- MFMA QKV projection, K-split ------------------------------
// Grid 1024 blocks x 256 thr. Block = 16 rows x 192 cols; 4 waves each own a
// K-quarter (8 k-steps of 32). Wave: 1 m-frag x 12 nt = 12 MFMA/step.
// Entire A slice (16 float4/lane) preloaded with STATIC register indices
// (fully unrolled loop -> no scratch). LDS tree-reduce combines K-partials.
__global__ __launch_bounds__(256, 2) void proj_kernel(
    const float* __restrict__ x, const short* __restrict__ Wt,
    short* __restrict__ qb, short* __restrict__ kb, short* __restrict__ vtb) {
  __shared__ floatx4 red[2][12][64];   // 24576 B

  const int t = threadIdx.x, lane = t & 63, w = t >> 6;
  const int lo = lane & 15, quad = lane >> 4;
  const int m0 = blockIdx.x * 16;
  const int k0 = w * 256;

  const float* __restrict__ xr = x + (size_t)(m0 + lo) * EMB + k0 + quad * 8;
  const short* __restrict__ wr = Wt + (size_t)lo * EMB + k0 + quad * 8;

  floatx4 acc[12];
#pragma unroll
  for (int nt = 0; nt < 12; ++nt) acc[nt] = (floatx4){0.f, 0.f, 0.f, 0.f};

  // full A preload: 16 dwordx4 in flight, static indices
  float4 a[8][2];
#pragma unroll
  for (int ks = 0; ks < 8; ++ks) {
    a[ks][0] = *(const float4*)(xr + ks * 32);
    a[ks][1] = *(const float4*)(xr + ks * 32 + 4);
  }

#pragma unroll
  for (int ks = 0; ks < 8; ++ks) {
    short8 bfr[12];
#pragma unroll
    for (int nt = 0; nt < 12; ++nt)
      bfr[nt] = *(const short8*)(wr + ks * 32 + (size_t)nt * 16 * EMB);
    short8 af;
    af[0] = f2bf(a[ks][0].x); af[1] = f2bf(a[ks][0].y);
    af[2] = f2bf(a[ks][0].z); af[3] = f2bf(a[ks][0].w);
    af[4] = f2bf(a[ks][1].x); af[5] = f2bf(a[ks][1].y);
    af[6] = f2bf(a[ks][1].z); af[7] = f2bf(a[ks][1].w);
#pragma unroll
    for (int nt = 0; nt < 12; ++nt)
      acc[nt] = __builtin_amdgcn_mfma_f32_16x16x32_bf16(af, bfr[nt], acc[nt], 0, 0, 0);
  }

  // ---- K-partial reduction. Round 1: w2->Red[0], w3->Red[1]; w0+=, w1+=.
  if (w >= 2) {
#pragma unroll
    for (int nt = 0; nt < 12; ++nt) red[w - 2][nt][lane] = acc[nt];
  }
  __syncthreads();
  if (w < 2) {
#pragma unroll
    for (int nt = 0; nt < 12; ++nt) acc[nt] += red[w][nt][lane];
    // Round 2 writes: w0 gives nt6..11, w1 gives nt0..5 (swap halves)
    if (w == 0) {
#pragma unroll
      for (int nt = 6; nt < 12; ++nt) red[0][nt - 6][lane] = acc[nt];
    } else {
#pragma unroll
      for (int nt = 0; nt < 6; ++nt) red[1][nt][lane] = acc[nt];
    }
  }
  __syncthreads();

  if (w < 2) {
    const int bb = m0 >> 11;
    const int s0 = (m0 & (SEQ - 1)) + quad * 4;
    const int rowb = m0 + quad * 4;
    if (w == 0) {   // final nt 0..5: q (0-3) + k-half (4,5)
      floatx4 fin[6];
#pragma unroll
      for (int nt = 0; nt < 6; ++nt) fin[nt] = acc[nt] + red[1][nt][lane];
#pragma unroll
      for (int nt = 0; nt < 4; ++nt)
#pragma unroll
        for (int r = 0; r < 4; ++r)
          qb[(size_t)(rowb + r) * HD + nt * 16 + lo] = f2bf(fin[nt][r] * 0.03125f);
#pragma unroll
      for (int nt = 4; nt < 6; ++nt)
#pragma unroll
        for (int r = 0; r < 4; ++r)
          kb[(size_t)(rowb + r) * HD + (nt - 4) * 16 + lo] = f2bf(fin[nt][r]);
    } else {        // final nt 6..11: k-half (6,7) + v transposed (8-11)
      floatx4 fin[6];
#pragma unroll
      for (int nt = 0; nt < 6; ++nt) fin[nt] = acc[nt + 6] + red[0][nt][lane];
#pragma unroll
      for (int nt = 0; nt < 2; ++nt)
#pragma unroll
        for (int r = 0; r < 4; ++r)
          kb[(size_t)(rowb + r) * HD + (nt + 2) * 16 + lo] = f2bf(fin[nt][r]);
#pragma unroll
      for (int nt = 2; nt < 6; ++nt) {
        const int col = (nt - 2) * 16 + lo;
        short4 sv = make_short4(f2bf(fin[nt][0]), f2bf(fin[nt][1]),
                                f2bf(fin[nt][2]), f2bf(fin[nt][3]));
        *(short4*)(vtb + ((size_t)bb * HD + col) * SEQ + s0) = sv;
      }
    }
  }
}

// ---------------- MFMA flash attention, key-half split (unchanged R6) -------
#define KSTR 72
#define PSTR 40

__global__ __launch_bounds__(256, 2) void attn_kernel(
    const short* __restrict__ qb, const short* __restrict__ kb,
    const short* __restrict__ vtb, float* __restrict__ out) {
  __shared__ __align__(16) short Ks[2][64 * KSTR];
  __shared__ __align__(16) short Vs[2][64 * KSTR];
  __shared__ __align__(16) short Ps[4][16 * PSTR];
  __shared__ __align__(16) floatx4 Red[2][5][64];

  const int b = blockIdx.y;
  const int bx = blockIdx.x;
  const int qx = (bx & 1) ? (63 - (bx >> 1)) : (bx >> 1);  // pair light+heavy
  const int q0 = qx * 32;
  const int t = threadIdx.x, lane = t & 63, w = t >> 6;
  const int wr = w >> 1, wk = w & 1;
  const int lo = lane & 15, quad = lane >> 4;

  const short* qp = qb + ((size_t)b * SEQ + q0 + wr * 16 + lo) * HD + quad * 8;
  const short8 qf0 = *(const short8*)(qp);
  const short8 qf1 = *(const short8*)(qp + 32);

  const int r0 = t >> 3, c0 = (t & 7) * 8;
  const int r1 = r0 + 32;
  const short* __restrict__ kgb = kb + (size_t)b * SEQ * HD;
  const short* __restrict__ vgb = vtb + (size_t)b * HD * SEQ;

  floatx4 acc[4];
  float lsum[4] = {0.f, 0.f, 0.f, 0.f};
#pragma unroll
  for (int nt = 0; nt < 4; ++nt) acc[nt] = (floatx4){0.f, 0.f, 0.f, 0.f};

  {
    short8 k0v = *(const short8*)(kgb + (size_t)r0 * HD + c0);
    short8 k1v = *(const short8*)(kgb + (size_t)r1 * HD + c0);
    short8 v0v = *(const short8*)(vgb + (size_t)r0 * SEQ + c0);
    short8 v1v = *(const short8*)(vgb + (size_t)r1 * SEQ + c0);
    *(short8*)(&Ks[0][r0 * KSTR + c0]) = k0v;
    *(short8*)(&Ks[0][r1 * KSTR + c0]) = k1v;
    *(short8*)(&Vs[0][r0 * KSTR + c0]) = v0v;
    *(short8*)(&Vs[0][r1 * KSTR + c0]) = v1v;
  }

  const int niter = q0 / 64 + 1;
  for (int it = 0; it < niter; ++it) {
    const int j0 = it * 64;
    const int buf = it & 1;
    __syncthreads();

    short8 kfr[2][2], vfr[4];
#pragma unroll
    for (int n2 = 0; n2 < 2; ++n2) {
      const short* kr = &Ks[buf][(wk * 32 + n2 * 16 + lo) * KSTR + quad * 8];
      kfr[n2][0] = *(const short8*)(kr);
      kfr[n2][1] = *(const short8*)(kr + 32);
    }
#pragma unroll
    for (int nt = 0; nt < 4; ++nt)
      vfr[nt] = *(const short8*)(&Vs[buf][(nt * 16 + lo) * KSTR + wk * 32 + quad * 8]);

    short8 nk0, nk1, nv0, nv1;
    const bool more = (it + 1 < niter);
    if (more) {
      const int jn = j0 + 64;
      nk0 = *(const short8*)(kgb + (size_t)(jn + r0) * HD + c0);
      nk1 = *(const short8*)(kgb + (size_t)(jn + r1) * HD + c0);
      nv0 = *(const short8*)(vgb + (size_t)r0 * SEQ + jn + c0);
      nv1 = *(const short8*)(vgb + (size_t)r1 * SEQ + jn + c0);
    }

    floatx4 s0 = (floatx4){0.f, 0.f, 0.f, 0.f};
    floatx4 s1 = (floatx4){0.f, 0.f, 0.f, 0.f};
    s0 = __builtin_amdgcn_mfma_f32_16x16x32_bf16(qf0, kfr[0][0], s0, 0, 0, 0);
    s0 = __builtin_amdgcn_mfma_f32_16x16x32_bf16(qf1, kfr[0][1], s0, 0, 0, 0);
    s1 = __builtin_amdgcn_mfma_f32_16x16x32_bf16(qf0, kfr[1][0], s1, 0, 0, 0);
    s1 = __builtin_amdgcn_mfma_f32_16x16x32_bf16(qf1, kfr[1][1], s1, 0, 0, 0);

    const bool diag = (j0 + 64 > q0);
    const int rowb = q0 + wr * 16 + quad * 4;
    short* Pw = Ps[w];
#pragma unroll
    for (int r = 0; r < 4; ++r) {
      float e0 = __expf(s0[r]);
      float e1 = __expf(s1[r]);
      if (diag) {
        const int key0 = j0 + wk * 32 + lo;
        e0 = (key0 <= rowb + r) ? e0 : 0.f;
        e1 = (key0 + 16 <= rowb + r) ? e1 : 0.f;
      }
      lsum[r] += e0 + e1;
      Pw[(quad * 4 + r) * PSTR + lo] = f2bf(e0);
      Pw[(quad * 4 + r) * PSTR + 16 + lo] = f2bf(e1);
    }
    const short8 pf = *(const short8*)(&Pw[lo * PSTR + quad * 8]);
#pragma unroll
    for (int nt = 0; nt < 4; ++nt)
      acc[nt] = __builtin_amdgcn_mfma_f32_16x16x32_bf16(pf, vfr[nt], acc[nt], 0, 0, 0);

    if (more) {
      const int nb = buf ^ 1;
      *(short8*)(&Ks[nb][r0 * KSTR + c0]) = nk0;
      *(short8*)(&Ks[nb][r1 * KSTR + c0]) = nk1;
      *(short8*)(&Vs[nb][r0 * KSTR + c0]) = nv0;
      *(short8*)(&Vs[nb][r1 * KSTR + c0]) = nv1;
    }
  }

#pragma unroll
  for (int d = 1; d < 16; d <<= 1) {
#pragma unroll
    for (int r = 0; r < 4; ++r) lsum[r] += __shfl_xor(lsum[r], d);
  }

  if (wk == 1) {
#pragma unroll
    for (int nt = 0; nt < 4; ++nt) Red[wr][nt][lane] = acc[nt];
    Red[wr][4][lane] = (floatx4){lsum[0], lsum[1], lsum[2], lsum[3]};
  }
  __syncthreads();
  if (wk == 0) {
    const floatx4 lp = Red[wr][4][lane];
    const int rowb = q0 + wr * 16 + quad * 4;
#pragma unroll
    for (int nt = 0; nt < 4; ++nt) {
      const floatx4 o = acc[nt] + Red[wr][nt][lane];
#pragma unroll
      for (int r = 0; r < 4; ++r)
        out[((size_t)b * SEQ + rowb + r) * HD + nt * 16 + lo] =
            o[r] / (lsum[r] + lp[r]);
    }
  }
}

extern "C" void kernel_launch(void* const* d_in, const int* in_sizes, int n_in,
                              void* d_out, int out_size, void* d_ws, size_t ws_size,
                              hipStream_t stream) {
  const float* x  = (const float*)d_in[0];
  const float* Wq = (const float*)d_in[1];
  const float* Wk = (const float*)d_in[2];
  const float* Wv = (const float*)d_in[3];
  float* out = (float*)d_out;
  short* ws = (short*)d_ws;
  short* qbp = ws;
  short* kbp = ws + (size_t)ROWS * HD;
  short* vtp = ws + (size_t)2 * ROWS * HD;
  short* Wt  = ws + (size_t)3 * ROWS * HD;   // total 6.68 MB <= ws_size

  wt_kernel<<<dim3(NTOT), 256, 0, stream>>>(Wq, Wk, Wv, Wt);
  proj_kernel<<<dim3(ROWS / 16), 256, 0, stream>>>(x, Wt, qbp, kbp, vtp);
  attn_kernel<<<dim3(SEQ / 32, BATCH), 256, 0, stream>>>(qbp, kbp, vtp, out);
}

// Round 8
// 156.524 us; speedup vs baseline: 1.1207x; 1.1207x over previous
//
#include <hip/hip_runtime.h>
#include <hip/hip_bf16.h>

// HeadLayer: B=8, S=2048, E=1024, H=64.
// Inputs (fp32): x[B,S,E], Wq[E,H], Wk[E,H], Wv[E,H]. Output (fp32): [B,S,H].
// ws (bf16): qb[B,S,H] (pre-scaled 1/32), kb[B,S,H], vtb[B,H,S], Wt[192][1024].

#define BATCH 8
#define SEQ   2048
#define EMB   1024
#define HD    64
#define ROWS  (BATCH*SEQ)      // 16384
#define NTOT  192

typedef __attribute__((ext_vector_type(8))) short short8;   // 8 bf16 (4 VGPR)
typedef __attribute__((ext_vector_type(4))) float floatx4;  // MFMA C/D frag

static __device__ __forceinline__ short f2bf(float f) {
  union { __hip_bfloat16 h; short s; } u;
  u.h = __float2bfloat16(f);
  return u.s;
}

// ---------------- W transpose pre-pass --------------------------------------
__global__ __launch_bounds__(256) void wt_kernel(
    const float* __restrict__ Wq, const float* __restrict__ Wk,
    const float* __restrict__ Wv, short* __restrict__ Wt) {
  const int i = blockIdx.x * 256 + threadIdx.x;   // 0..49151
  const int np = i % NTOT;
  const int c4 = i / NTOT;                        // 0..255
  const float* __restrict__ W = (np < 64) ? Wq : ((np < 128) ? Wk : Wv);
  const int n = np & 63;
  short4 o;
  o.x = f2bf(W[(c4 * 4 + 0) * HD + n]);
  o.y = f2bf(W[(c4 * 4 + 1) * HD + n]);
  o.z = f2bf(W[(c4 * 4 + 2) * HD + n]);
  o.w = f2bf(W[(c4 * 4 + 3) * HD + n]);
  *(short4*)(Wt + (size_t)np * EMB + c4 * 4) = o;
}

// ---------------- MFMA QKV projection, n-split + LDS-staged A ---------------
// Grid 512 blocks (2/CU, 8 waves/CU). Block = 32 rows x 192 cols, full K.
// Wave w owns n-tiles 3w..3w+2, both m-frags -> 6 acc, NO reduction.
// A (x) staged fp32->bf16 into LDS once per k-step (shared by all 4 waves);
// B from L2-hot Wt with depth-1 prefetch in named scalars (no reg arrays).
// B L2 traffic = 512 blocks x 384 KB = 192 MB (vs R7's 1.5 GB).
#define ASTR 40   // LDS row stride in shorts (80 B: 16B-aligned, conflict-benign)

__global__ __launch_bounds__(256, 2) void proj_kernel(
    const float* __restrict__ x, const short* __restrict__ Wt,
    short* __restrict__ qb, short* __restrict__ kb, short* __restrict__ vtb) {
  __shared__ __align__(16) short As[2][32 * ASTR];   // 5120 B

  const int t = threadIdx.x, lane = t & 63, w = t >> 6;
  const int lo = lane & 15, quad = lane >> 4;
  const int m0 = blockIdx.x * 32;

  // staging coords: thread t loads x[m0 + srow][ks*32 + sc4*4 ..+3]
  const int srow = t >> 3, sc4 = t & 7;
  const float* __restrict__ xs = x + (size_t)(m0 + srow) * EMB + sc4 * 4;

  // B pointers: wave w covers n-tiles 3w, 3w+1, 3w+2
  const short* __restrict__ wb = Wt + (size_t)(w * 3 * 16 + lo) * EMB + quad * 8;

  floatx4 acc[2][3];
#pragma unroll
  for (int mf = 0; mf < 2; ++mf)
#pragma unroll
    for (int j = 0; j < 3; ++j) acc[mf][j] = (floatx4){0.f, 0.f, 0.f, 0.f};

  // ---- prestage k-step 0 into buf 0
  {
    const float4 xv = *(const float4*)(xs);
    *(short4*)(&As[0][srow * ASTR + sc4 * 4]) =
        make_short4(f2bf(xv.x), f2bf(xv.y), f2bf(xv.z), f2bf(xv.w));
  }
  // ---- B prefetch for step 0 (named scalars)
  short8 b0 = *(const short8*)(wb);
  short8 b1 = *(const short8*)(wb + (size_t)16 * EMB);
  short8 b2 = *(const short8*)(wb + (size_t)32 * EMB);

  for (int ks = 0; ks < 32; ++ks) {
    const int buf = ks & 1;
    __syncthreads();   // staged buf visible; all waves done reading buf^1

    // issue next-step loads early (latency hidden behind MFMA)
    float4 xn;
    short8 nb0, nb1, nb2;
    if (ks < 31) {
      const int ko = (ks + 1) * 32;
      xn = *(const float4*)(xs + ko);
      nb0 = *(const short8*)(wb + ko);
      nb1 = *(const short8*)(wb + ko + (size_t)16 * EMB);
      nb2 = *(const short8*)(wb + ko + (size_t)32 * EMB);
    }

    // A frags from LDS (bf16, frag-ready)
    const short8 af0 = *(const short8*)(&As[buf][(lo) * ASTR + quad * 8]);
    const short8 af1 = *(const short8*)(&As[buf][(16 + lo) * ASTR + quad * 8]);

    acc[0][0] = __builtin_amdgcn_mfma_f32_16x16x32_bf16(af0, b0, acc[0][0], 0, 0, 0);
    acc[1][0] = __builtin_amdgcn_mfma_f32_16x16x32_bf16(af1, b0, acc[1][0], 0, 0, 0);
    acc[0][1] = __builtin_amdgcn_mfma_f32_16x16x32_bf16(af0, b1, acc[0][1], 0, 0, 0);
    acc[1][1] = __builtin_amdgcn_mfma_f32_16x16x32_bf16(af1, b1, acc[1][1], 0, 0, 0);
    acc[0][2] = __builtin_amdgcn_mfma_f32_16x16x32_bf16(af0, b2, acc[0][2], 0, 0, 0);
    acc[1][2] = __builtin_amdgcn_mfma_f32_16x16x32_bf16(af1, b2, acc[1][2], 0, 0, 0);

    if (ks < 31) {
      // stage next A into the other buffer (safe: all waves past this ks's
      // barrier have finished reading buf^1 during step ks-1)
      *(short4*)(&As[buf ^ 1][srow * ASTR + sc4 * 4]) =
          make_short4(f2bf(xn.x), f2bf(xn.y), f2bf(xn.z), f2bf(xn.w));
      b0 = nb0; b1 = nb1; b2 = nb2;
    }
  }

  // ---- epilogue: wave-private n-tiles, direct stores (no reduction)
  const int bb = m0 >> 11;
  const int sbase = (m0 & (SEQ - 1)) + quad * 4;
#pragma unroll
  for (int mf = 0; mf < 2; ++mf) {
    const int rowb = m0 + mf * 16 + quad * 4;
#pragma unroll
    for (int j = 0; j < 3; ++j) {
      const int nt = w * 3 + j;
      const floatx4 v = acc[mf][j];
      if (nt < 4) {
#pragma unroll
        for (int r = 0; r < 4; ++r)
          qb[(size_t)(rowb + r) * HD + nt * 16 + lo] = f2bf(v[r] * 0.03125f);
      } else if (nt < 8) {
#pragma unroll
        for (int r = 0; r < 4; ++r)
          kb[(size_t)(rowb + r) * HD + (nt - 4) * 16 + lo] = f2bf(v[r]);
      } else {
        const int col = (nt - 8) * 16 + lo;
        short4 sv = make_short4(f2bf(v[0]), f2bf(v[1]), f2bf(v[2]), f2bf(v[3]));
        *(short4*)(vtb + ((size_t)bb * HD + col) * SEQ + sbase + mf * 16) = sv;
      }
    }
  }
}

// ---------------- MFMA flash attention, key-half split (unchanged R6) -------
#define KSTR 72
#define PSTR 40

__global__ __launch_bounds__(256, 2) void attn_kernel(
    const short* __restrict__ qb, const short* __restrict__ kb,
    const short* __restrict__ vtb, float* __restrict__ out) {
  __shared__ __align__(16) short Ks[2][64 * KSTR];
  __shared__ __align__(16) short Vs[2][64 * KSTR];
  __shared__ __align__(16) short Ps[4][16 * PSTR];
  __shared__ __align__(16) floatx4 Red[2][5][64];

  const int b = blockIdx.y;
  const int bx = blockIdx.x;
  const int qx = (bx & 1) ? (63 - (bx >> 1)) : (bx >> 1);  // pair light+heavy
  const int q0 = qx * 32;
  const int t = threadIdx.x, lane = t & 63, w = t >> 6;
  const int wr = w >> 1, wk = w & 1;
  const int lo = lane & 15, quad = lane >> 4;

  const short* qp = qb + ((size_t)b * SEQ + q0 + wr * 16 + lo) * HD + quad * 8;
  const short8 qf0 = *(const short8*)(qp);
  const short8 qf1 = *(const short8*)(qp + 32);

  const int r0 = t >> 3, c0 = (t & 7) * 8;
  const int r1 = r0 + 32;
  const short* __restrict__ kgb = kb + (size_t)b * SEQ * HD;
  const short* __restrict__ vgb = vtb + (size_t)b * HD * SEQ;

  floatx4 acc[4];
  float lsum[4] = {0.f, 0.f, 0.f, 0.f};
#pragma unroll
  for (int nt = 0; nt < 4; ++nt) acc[nt] = (floatx4){0.f, 0.f, 0.f, 0.f};

  {
    short8 k0v = *(const short8*)(kgb + (size_t)r0 * HD + c0);
    short8 k1v = *(const short8*)(kgb + (size_t)r1 * HD + c0);
    short8 v0v = *(const short8*)(vgb + (size_t)r0 * SEQ + c0);
    short8 v1v = *(const short8*)(vgb + (size_t)r1 * SEQ + c0);
    *(short8*)(&Ks[0][r0 * KSTR + c0]) = k0v;
    *(short8*)(&Ks[0][r1 * KSTR + c0]) = k1v;
    *(short8*)(&Vs[0][r0 * KSTR + c0]) = v0v;
    *(short8*)(&Vs[0][r1 * KSTR + c0]) = v1v;
  }

  const int niter = q0 / 64 + 1;
  for (int it = 0; it < niter; ++it) {
    const int j0 = it * 64;
    const int buf = it & 1;
    __syncthreads();

    short8 kfr[2][2], vfr[4];
#pragma unroll
    for (int n2 = 0; n2 < 2; ++n2) {
      const short* kr = &Ks[buf][(wk * 32 + n2 * 16 + lo) * KSTR + quad * 8];
      kfr[n2][0] = *(const short8*)(kr);
      kfr[n2][1] = *(const short8*)(kr + 32);
    }
#pragma unroll
    for (int nt = 0; nt < 4; ++nt)
      vfr[nt] = *(const short8*)(&Vs[buf][(nt * 16 + lo) * KSTR + wk * 32 + quad * 8]);

    short8 nk0, nk1, nv0, nv1;
    const bool more = (it + 1 < niter);
    if (more) {
      const int jn = j0 + 64;
      nk0 = *(const short8*)(kgb + (size_t)(jn + r0) * HD + c0);
      nk1 = *(const short8*)(kgb + (size_t)(jn + r1) * HD + c0);
      nv0 = *(const short8*)(vgb + (size_t)r0 * SEQ + jn + c0);
      nv1 = *(const short8*)(vgb + (size_t)r1 * SEQ + jn + c0);
    }

    floatx4 s0 = (floatx4){0.f, 0.f, 0.f, 0.f};
    floatx4 s1 = (floatx4){0.f, 0.f, 0.f, 0.f};
    s0 = __builtin_amdgcn_mfma_f32_16x16x32_bf16(qf0, kfr[0][0], s0, 0, 0, 0);
    s0 = __builtin_amdgcn_mfma_f32_16x16x32_bf16(qf1, kfr[0][1], s0, 0, 0, 0);
    s1 = __builtin_amdgcn_mfma_f32_16x16x32_bf16(qf0, kfr[1][0], s1, 0, 0, 0);
    s1 = __builtin_amdgcn_mfma_f32_16x16x32_bf16(qf1, kfr[1][1], s1, 0, 0, 0);

    const bool diag = (j0 + 64 > q0);
    const int rowb = q0 + wr * 16 + quad * 4;
    short* Pw = Ps[w];
#pragma unroll
    for (int r = 0; r < 4; ++r) {
      float e0 = __expf(s0[r]);
      float e1 = __expf(s1[r]);
      if (diag) {
        const int key0 = j0 + wk * 32 + lo;
        e0 = (key0 <= rowb + r) ? e0 : 0.f;
        e1 = (key0 + 16 <= rowb + r) ? e1 : 0.f;
      }
      lsum[r] += e0 + e1;
      Pw[(quad * 4 + r) * PSTR + lo] = f2bf(e0);
      Pw[(quad * 4 + r) * PSTR + 16 + lo] = f2bf(e1);
    }
    const short8 pf = *(const short8*)(&Pw[lo * PSTR + quad * 8]);
#pragma unroll
    for (int nt = 0; nt < 4; ++nt)
      acc[nt] = __builtin_amdgcn_mfma_f32_16x16x32_bf16(pf, vfr[nt], acc[nt], 0, 0, 0);

    if (more) {
      const int nb = buf ^ 1;
      *(short8*)(&Ks[nb][r0 * KSTR + c0]) = nk0;
      *(short8*)(&Ks[nb][r1 * KSTR + c0]) = nk1;
      *(short8*)(&Vs[nb][r0 * KSTR + c0]) = nv0;
      *(short8*)(&Vs[nb][r1 * KSTR + c0]) = nv1;
    }
  }

#pragma unroll
  for (int d = 1; d < 16; d <<= 1) {
#pragma unroll
    for (int r = 0; r < 4; ++r) lsum[r] += __shfl_xor(lsum[r], d);
  }

  if (wk == 1) {
#pragma unroll
    for (int nt = 0; nt < 4; ++nt) Red[wr][nt][lane] = acc[nt];
    Red[wr][4][lane] = (floatx4){lsum[0], lsum[1], lsum[2], lsum[3]};
  }
  __syncthreads();
  if (wk == 0) {
    const floatx4 lp = Red[wr][4][lane];
    const int rowb = q0 + wr * 16 + quad * 4;
#pragma unroll
    for (int nt = 0; nt < 4; ++nt) {
      const floatx4 o = acc[nt] + Red[wr][nt][lane];
#pragma unroll
      for (int r = 0; r < 4; ++r)
        out[((size_t)b * SEQ + rowb + r) * HD + nt * 16 + lo] =
            o[r] / (lsum[r] + lp[r]);
    }
  }
}

extern "C" void kernel_launch(void* const* d_in, const int* in_sizes, int n_in,
                              void* d_out, int out_size, void* d_ws, size_t ws_size,
                              hipStream_t stream) {
  const float* x  = (const float*)d_in[0];
  const float* Wq = (const float*)d_in[1];
  const float* Wk = (const float*)d_in[2];
  const float* Wv = (const float*)d_in[3];
  float* out = (float*)d_out;
  short* ws = (short*)d_ws;
  short* qbp = ws;
  short* kbp = ws + (size_t)ROWS * HD;
  short* vtp = ws + (size_t)2 * ROWS * HD;
  short* Wt  = ws + (size_t)3 * ROWS * HD;   // total 6.68 MB <= ws_size

  wt_kernel<<<dim3(NTOT), 256, 0, stream>>>(Wq, Wk, Wv, Wt);
  proj_kernel<<<dim3(ROWS / 32), 256, 0, stream>>>(x, Wt, qbp, kbp, vtp);
  attn_kernel<<<dim3(SEQ / 32, BATCH), 256, 0, stream>>>(qbp, kbp, vtp, out);
}